// Round 5
// baseline (278.509 us; speedup 1.0000x reference)
//
#include <hip/hip_runtime.h>

#define NCLS 10
#define TPB  256
#define NBLK 2048
#define ACC_STRIDE 64   // floats between global accumulator slots (256 B)

typedef float vfloat4 __attribute__((ext_vector_type(4)));
typedef int   vint4   __attribute__((ext_vector_type(4)));

// ws layout: ((unsigned*)ws)[0] = block completion counter.
// Accumulator slot j in [0,20) lives at ws[(j+1)*ACC_STRIDE]:
//   j<10 : class-j sqerr sum ; j>=10 : class-(j-10) count.
// All zeroed by a 5.4 KB hipMemsetAsync per call.

__device__ __forceinline__ void proc_elem(float o, float t, int m,
                                          float sum[NCLS], unsigned long long &cnt)
{
    float d  = o - t;
    float sq = d * d;
    int cls  = (m == 1) ? (int)t : NCLS;     // 10 = dummy
    cnt += 1ull << (6 * cls);                // 10x 6-bit counters; dummy spills off the top harmlessly
#pragma unroll
    for (int c = 0; c < NCLS; ++c)
        sum[c] += (cls == c) ? sq : 0.0f;    // v_cmp + v_cndmask + v_add
}

__global__ __launch_bounds__(TPB) void loss_main_kernel(
    const float* __restrict__ outputs,
    const float* __restrict__ targets,
    const int*   __restrict__ mask,
    float* __restrict__ ws,
    float* __restrict__ out,
    int n4, int n_rem_base, int n_rem)
{
    const vfloat4* o4 = (const vfloat4*)outputs;
    const vfloat4* t4 = (const vfloat4*)targets;
    const vint4*   m4 = (const vint4*)mask;

    const int tid = blockIdx.x * TPB + threadIdx.x;
    const int T   = NBLK * TPB;

    float sum[NCLS];
#pragma unroll
    for (int c = 0; c < NCLS; ++c) sum[c] = 0.0f;
    unsigned long long cnt = 0;

    if (n4 == 8 * T) {
        // Benchmark shape: exactly 8 float4-groups per thread.
        // 3-deep rotating pipeline -> 9 loads in flight per wave.
        vfloat4 ob[3], tb[3];
        vint4   mb[3];
#pragma unroll
        for (int p = 0; p < 3; ++p) {
            int i = tid + p * T;
            ob[p] = __builtin_nontemporal_load(&o4[i]);
            tb[p] = __builtin_nontemporal_load(&t4[i]);
            mb[p] = __builtin_nontemporal_load(&m4[i]);
        }
#pragma unroll
        for (int g = 0; g < 8; ++g) {
            const int s = g % 3;
            vfloat4 o = ob[s], t = tb[s];
            vint4   m = mb[s];
            if (g + 3 < 8) {           // refill the slot we just consumed
                int i = tid + (g + 3) * T;
                ob[s] = __builtin_nontemporal_load(&o4[i]);
                tb[s] = __builtin_nontemporal_load(&t4[i]);
                mb[s] = __builtin_nontemporal_load(&m4[i]);
            }
            proc_elem(o.x, t.x, m.x, sum, cnt);
            proc_elem(o.y, t.y, m.y, sum, cnt);
            proc_elem(o.z, t.z, m.z, sum, cnt);
            proc_elem(o.w, t.w, m.w, sum, cnt);
        }
    } else {
        // generic fallback for any size
        for (int i = tid; i < n4; i += T) {
            vfloat4 o = __builtin_nontemporal_load(&o4[i]);
            vfloat4 t = __builtin_nontemporal_load(&t4[i]);
            vint4   m = __builtin_nontemporal_load(&m4[i]);
            proc_elem(o.x, t.x, m.x, sum, cnt);
            proc_elem(o.y, t.y, m.y, sum, cnt);
            proc_elem(o.z, t.z, m.z, sum, cnt);
            proc_elem(o.w, t.w, m.w, sum, cnt);
        }
    }
    // scalar tail (n % 4); empty for the benchmark
    if (tid < n_rem)
        proc_elem(outputs[n_rem_base + tid], targets[n_rem_base + tid],
                  mask[n_rem_base + tid], sum, cnt);

    // unpack packed counters to floats
    float cfl[NCLS];
#pragma unroll
    for (int c = 0; c < NCLS; ++c)
        cfl[c] = (float)((unsigned)(cnt >> (6 * c)) & 63u);

    // wave reduction
#pragma unroll
    for (int c = 0; c < NCLS; ++c) {
#pragma unroll
        for (int off = 32; off > 0; off >>= 1) {
            sum[c] += __shfl_down(sum[c], off, 64);
            cfl[c] += __shfl_down(cfl[c], off, 64);
        }
    }

    // cross-wave reduction + 20 device-scope atomics per block
    __shared__ float lsS[4][NCLS];
    __shared__ float lsC[4][NCLS];
    __shared__ int   amLast;
    int wave = threadIdx.x >> 6;
    int lane = threadIdx.x & 63;
    if (lane == 0) {
#pragma unroll
        for (int c = 0; c < NCLS; ++c) {
            lsS[wave][c] = sum[c];
            lsC[wave][c] = cfl[c];
        }
    }
    __syncthreads();

    if (threadIdx.x < 2 * NCLS) {
        int c = (threadIdx.x < NCLS) ? threadIdx.x : (threadIdx.x - NCLS);
        float v;
        if (threadIdx.x < NCLS)
            v = lsS[0][c] + lsS[1][c] + lsS[2][c] + lsS[3][c];
        else
            v = lsC[0][c] + lsC[1][c] + lsC[2][c] + lsC[3][c];
        atomicAdd(&ws[(threadIdx.x + 1) * ACC_STRIDE], v);
    }

    // __syncthreads drains vmcnt -> this block's ws atomics are complete
    __syncthreads();
    if (threadIdx.x == 0) {
        __threadfence();
        unsigned done = atomicAdd((unsigned*)ws, 1u);
        amLast = (done == (unsigned)(NBLK - 1)) ? 1 : 0;
    }
    __syncthreads();

    if (amLast && threadIdx.x < 64) {
        // last block: finalize. atomicAdd(p, 0.0f) = coherent device-scope read.
        float le = 0.0f;
        if (lane < NCLS) {
            float s  = atomicAdd(&ws[(1 + lane) * ACC_STRIDE], 0.0f);
            float cn = atomicAdd(&ws[(1 + NCLS + lane) * ACC_STRIDE], 0.0f);
            le = (cn > 0.0f) ? (s / fmaxf(cn, 1.0f)) : 0.0f;
            out[1 + lane]  = le;        // loss_each
            out[11 + lane] = cn;        // class_n
        }
        float w = 0.1f * le;            // WEIGHT = 0.1 per class
#pragma unroll
        for (int off = 32; off > 0; off >>= 1) w += __shfl_down(w, off, 64);
        if (lane == 0) out[0] = w;      // loss
    }
}

extern "C" void kernel_launch(void* const* d_in, const int* in_sizes, int n_in,
                              void* d_out, int out_size, void* d_ws, size_t ws_size,
                              hipStream_t stream)
{
    const float* outputs = (const float*)d_in[0];
    const float* targets = (const float*)d_in[1];
    const int*   mask    = (const int*)d_in[2];
    float* out = (float*)d_out;
    float* ws  = (float*)d_ws;

    int n  = in_sizes[0];
    int n4 = n / 4;
    int n_rem_base = 4 * n4;
    int n_rem = n - n_rem_base;

    // zero counter + 20 accumulator slots
    hipMemsetAsync(d_ws, 0, (2 * NCLS + 1) * ACC_STRIDE * sizeof(float), stream);
    loss_main_kernel<<<NBLK, TPB, 0, stream>>>(outputs, targets, mask, ws, out,
                                               n4, n_rem_base, n_rem);
}

// Round 6
// 195.942 us; speedup vs baseline: 1.4214x; 1.4214x over previous
//
#include <hip/hip_runtime.h>

#define NCLS 10
#define TPB  256
#define NBLK 2048
#define ACC_STRIDE 64   // floats between global accumulator slots (256 B)

typedef float vfloat4 __attribute__((ext_vector_type(4)));
typedef int   vint4   __attribute__((ext_vector_type(4)));

// ws: slot j in [0,20): j<10 class sqerr sum, j>=10 class count. ws[j*ACC_STRIDE].

__device__ __forceinline__ void proc_elem(float o, float t, int m,
                                          float sum[NCLS], unsigned long long &cnt)
{
    float d  = o - t;
    float sq = d * d;
    int cls  = (m == 1) ? (int)t : NCLS;     // 10 = dummy
    cnt += 1ull << (6 * cls);                // 10x 6-bit counters; dummy spills off the top
#pragma unroll
    for (int c = 0; c < NCLS; ++c)
        sum[c] += (cls == c) ? sq : 0.0f;    // v_cmp + v_cndmask + v_add
}

__device__ __forceinline__ void proc_group(const vfloat4 &o, const vfloat4 &t,
                                           const vint4 &m,
                                           float sum[NCLS], unsigned long long &cnt)
{
    proc_elem(o.x, t.x, m.x, sum, cnt);
    proc_elem(o.y, t.y, m.y, sum, cnt);
    proc_elem(o.z, t.z, m.z, sum, cnt);
    proc_elem(o.w, t.w, m.w, sum, cnt);
}

#define LOADG(o_, t_, m_, r_) do { int _i = tid + (r_) * T;          \
        o_ = __builtin_nontemporal_load(&o4[_i]);                    \
        t_ = __builtin_nontemporal_load(&t4[_i]);                    \
        m_ = __builtin_nontemporal_load(&m4[_i]); } while (0)

// min 4 waves/EU -> 128-VGPR budget: lets the scheduler keep 4 slots
// (48 buffer VGPRs) live with loads hoisted. Default budget (8 waves/EU,
// ~64 VGPR) silently sinks the loads and kills MLP (R5 post-mortem).
__global__ __launch_bounds__(TPB, 4) void loss_main_kernel(
    const float* __restrict__ outputs,
    const float* __restrict__ targets,
    const int*   __restrict__ mask,
    float* __restrict__ ws,
    int n4, int n_rem_base, int n_rem)
{
    const vfloat4* o4 = (const vfloat4*)outputs;
    const vfloat4* t4 = (const vfloat4*)targets;
    const vint4*   m4 = (const vint4*)mask;

    const int tid = blockIdx.x * TPB + threadIdx.x;
    const int T   = NBLK * TPB;

    float sum[NCLS];
#pragma unroll
    for (int c = 0; c < NCLS; ++c) sum[c] = 0.0f;
    unsigned long long cnt = 0;

    if (n4 == 8 * T) {
        // Benchmark shape: exactly 8 float4-groups/thread. Straight-line
        // 4-slot pipeline, named variables, no rotation indexing.
        vfloat4 oA, tA, oB, tB, oC, tC, oD, tD;
        vint4   mA, mB, mC, mD;
        LOADG(oA, tA, mA, 0);
        LOADG(oB, tB, mB, 1);
        LOADG(oC, tC, mC, 2);
        LOADG(oD, tD, mD, 3);

        proc_group(oA, tA, mA, sum, cnt); LOADG(oA, tA, mA, 4);
        proc_group(oB, tB, mB, sum, cnt); LOADG(oB, tB, mB, 5);
        proc_group(oC, tC, mC, sum, cnt); LOADG(oC, tC, mC, 6);
        proc_group(oD, tD, mD, sum, cnt); LOADG(oD, tD, mD, 7);

        proc_group(oA, tA, mA, sum, cnt);
        proc_group(oB, tB, mB, sum, cnt);
        proc_group(oC, tC, mC, sum, cnt);
        proc_group(oD, tD, mD, sum, cnt);
    } else {
        // generic fallback: A/B 2-deep pipeline (R4 structure)
        const int full  = n4 / T;
        const int kfull = full & ~1;
        if (kfull >= 2) {
            vfloat4 oA, tA, oB, tB;
            vint4   mA, mB;
            LOADG(oA, tA, mA, 0);
            LOADG(oB, tB, mB, 1);
            int k = 0;
            while (true) {
                proc_group(oA, tA, mA, sum, cnt);
                if (k + 2 < kfull) LOADG(oA, tA, mA, k + 2);
                proc_group(oB, tB, mB, sum, cnt);
                if (k + 3 < kfull) LOADG(oB, tB, mB, k + 3);
                k += 2;
                if (k >= kfull) break;
            }
        }
        for (int i = tid + kfull * T; i < n4; i += T) {
            vfloat4 o = __builtin_nontemporal_load(&o4[i]);
            vfloat4 t = __builtin_nontemporal_load(&t4[i]);
            vint4   m = __builtin_nontemporal_load(&m4[i]);
            proc_group(o, t, m, sum, cnt);
        }
    }
    // scalar tail (n % 4); empty for the benchmark
    if (tid < n_rem)
        proc_elem(outputs[n_rem_base + tid], targets[n_rem_base + tid],
                  mask[n_rem_base + tid], sum, cnt);

    // unpack packed counters to floats
    float cfl[NCLS];
#pragma unroll
    for (int c = 0; c < NCLS; ++c)
        cfl[c] = (float)((unsigned)(cnt >> (6 * c)) & 63u);

    // wave reduction
#pragma unroll
    for (int c = 0; c < NCLS; ++c) {
#pragma unroll
        for (int off = 32; off > 0; off >>= 1) {
            sum[c] += __shfl_down(sum[c], off, 64);
            cfl[c] += __shfl_down(cfl[c], off, 64);
        }
    }

    // cross-wave reduction + 20 global atomics per block
    __shared__ float lsS[4][NCLS];
    __shared__ float lsC[4][NCLS];
    int wave = threadIdx.x >> 6;
    int lane = threadIdx.x & 63;
    if (lane == 0) {
#pragma unroll
        for (int c = 0; c < NCLS; ++c) {
            lsS[wave][c] = sum[c];
            lsC[wave][c] = cfl[c];
        }
    }
    __syncthreads();

    if (threadIdx.x < 2 * NCLS) {
        int c = (threadIdx.x < NCLS) ? threadIdx.x : (threadIdx.x - NCLS);
        float v;
        if (threadIdx.x < NCLS)
            v = lsS[0][c] + lsS[1][c] + lsS[2][c] + lsS[3][c];
        else
            v = lsC[0][c] + lsC[1][c] + lsC[2][c] + lsC[3][c];
        atomicAdd(&ws[threadIdx.x * ACC_STRIDE], v);
    }
}

__global__ __launch_bounds__(64) void loss_final_kernel(
    const float* __restrict__ ws,
    float* __restrict__ out)
{
    int lane = threadIdx.x;   // single wave
    float le = 0.0f;
    if (lane < NCLS) {
        float s  = ws[lane * ACC_STRIDE];
        float cn = ws[(NCLS + lane) * ACC_STRIDE];
        le = (cn > 0.0f) ? (s / fmaxf(cn, 1.0f)) : 0.0f;
        out[1 + lane]  = le;        // loss_each
        out[11 + lane] = cn;        // class_n
    }
    float w = 0.1f * le;            // WEIGHT = 0.1 per class
#pragma unroll
    for (int off = 32; off > 0; off >>= 1) w += __shfl_down(w, off, 64);
    if (lane == 0) out[0] = w;      // loss
}

extern "C" void kernel_launch(void* const* d_in, const int* in_sizes, int n_in,
                              void* d_out, int out_size, void* d_ws, size_t ws_size,
                              hipStream_t stream)
{
    const float* outputs = (const float*)d_in[0];
    const float* targets = (const float*)d_in[1];
    const int*   mask    = (const int*)d_in[2];
    float* out = (float*)d_out;
    float* ws  = (float*)d_ws;

    int n  = in_sizes[0];
    int n4 = n / 4;
    int n_rem_base = 4 * n4;
    int n_rem = n - n_rem_base;

    hipMemsetAsync(d_ws, 0, 2 * NCLS * ACC_STRIDE * sizeof(float), stream);
    loss_main_kernel<<<NBLK, TPB, 0, stream>>>(outputs, targets, mask, ws,
                                               n4, n_rem_base, n_rem);
    loss_final_kernel<<<1, 64, 0, stream>>>(ws, out);
}